// Round 8
// baseline (2545.843 us; speedup 1.0000x reference)
//
#include <hip/hip_runtime.h>

#define IN_DIM 128
#define HID 64
#define OUT_DIM 128
#define NGRAPH 8

#define CHUNK 4096      // edges per chunk for binning passes
#define BSH 6           // 64 nodes per bucket
#define BSZ 64
#define MAXB 1600       // max buckets (N<=102400)

typedef unsigned long long u64;
typedef unsigned int u32;
typedef __attribute__((ext_vector_type(8))) short short8;   // 8 bf16
typedef __attribute__((ext_vector_type(4))) float f32x4;

__device__ inline short bf16b(float f) {                    // f32 -> bf16 bits
    u32 u = __float_as_uint(f);
    return (short)((u + 0x7FFFu + ((u >> 16) & 1u)) >> 16);
}
__device__ inline u32 pack_bf16(float a, float b) {         // low = a, high = b
    u32 ua = (__float_as_uint(a) + 0x8000u) >> 16;
    u32 ub = (__float_as_uint(b) + 0x8000u) & 0xFFFF0000u;
    return ua | ub;
}
__device__ inline float bf16_lo(u32 v) { return __uint_as_float(v << 16); }
__device__ inline float bf16_hi(u32 v) { return __uint_as_float(v & 0xFFFF0000u); }

// ---- Pass A: per-chunk coarse histogram of dst>>6 (LDS atomics only) -------
__global__ __launch_bounds__(256) void bhist_kernel(const int* __restrict__ dst,
                                                    u32* __restrict__ hist,
                                                    int E, int nchunk, int nbuck) {
    __shared__ u32 h[MAXB];
    for (int i = threadIdx.x; i < nbuck; i += 256) h[i] = 0;
    __syncthreads();
    int c = blockIdx.x;
    int beg = c * CHUNK, end = min(beg + CHUNK, E);
    for (int i = beg + threadIdx.x; i < end; i += 256)
        atomicAdd(&h[dst[i] >> BSH], 1u);
    __syncthreads();
    for (int b = threadIdx.x; b < nbuck; b += 256)
        hist[(size_t)b * nchunk + c] = h[b];
}

// ---- S1: per bucket, exclusive scan over chunks (<=1024, 2/thread) ---------
__global__ __launch_bounds__(512) void scanS1(u32* __restrict__ hist, u32* __restrict__ tot,
                                              int nchunk, int nbuck) {
    __shared__ u32 sm[1024];
    int b = blockIdx.x;
    int i0 = threadIdx.x, i1 = threadIdx.x + 512;
    u32 v0 = (i0 < nchunk) ? hist[(size_t)b * nchunk + i0] : 0;
    u32 v1 = (i1 < nchunk) ? hist[(size_t)b * nchunk + i1] : 0;
    sm[i0] = v0; sm[i1] = v1;
    __syncthreads();
    for (int off = 1; off < 1024; off <<= 1) {
        u32 t0 = (i0 >= off) ? sm[i0 - off] : 0;
        u32 t1 = (i1 >= off) ? sm[i1 - off] : 0;
        __syncthreads();
        sm[i0] += t0; sm[i1] += t1;
        __syncthreads();
    }
    if (i0 < nchunk) hist[(size_t)b * nchunk + i0] = sm[i0] - v0;
    if (i1 < nchunk) hist[(size_t)b * nchunk + i1] = sm[i1] - v1;
    if (threadIdx.x == 511) tot[b] = sm[1023];
}

// ---- S2: exclusive scan over bucket totals -> base[0..nbuck] (<=2048) ------
__global__ __launch_bounds__(1024) void scanS2(const u32* __restrict__ tot,
                                               u32* __restrict__ base, int nbuck) {
    __shared__ u32 sm[2048];
    int i0 = threadIdx.x, i1 = threadIdx.x + 1024;
    u32 v0 = (i0 < nbuck) ? tot[i0] : 0;
    u32 v1 = (i1 < nbuck) ? tot[i1] : 0;
    sm[i0] = v0; sm[i1] = v1;
    __syncthreads();
    for (int off = 1; off < 2048; off <<= 1) {
        u32 t0 = (i0 >= off) ? sm[i0 - off] : 0;
        u32 t1 = (i1 >= off) ? sm[i1 - off] : 0;
        __syncthreads();
        sm[i0] += t0; sm[i1] += t1;
        __syncthreads();
    }
    if (i0 <= nbuck) base[i0] = sm[i0] - v0;
    if (i1 <= nbuck) base[i1] = sm[i1] - v1;
}

// ---- Pass B: LDS counting-sort per chunk, then COALESCED write-out ---------
// record: { src | (dst&63)<<17 , ew_bits }   (src < 2^17)
__global__ __launch_bounds__(256) void bin_kernel(const int* __restrict__ src,
                                                  const int* __restrict__ dst,
                                                  const float* __restrict__ ew,
                                                  const u32* __restrict__ offs,
                                                  const u32* __restrict__ base,
                                                  int2* __restrict__ bse,
                                                  int E, int nchunk, int nbuck) {
    __shared__ u32 lcnt[MAXB];                // count, then cursor
    __shared__ u32 lpos[MAXB];                // chunk-local exclusive offsets
    __shared__ u32 gbase[MAXB];               // global target base for this chunk
    __shared__ u32 part[256];
    __shared__ int2 buf[CHUNK];               // bucket-sorted records (32 KB)
    __shared__ unsigned short bb[CHUNK];      // bucket id per sorted slot

    int c = blockIdx.x;
    int tid = threadIdx.x;
    int beg = c * CHUNK, end = min(beg + CHUNK, E);
    for (int b = tid; b < nbuck; b += 256) lcnt[b] = 0;
    __syncthreads();
    // pass 1: count buckets
    for (int i = beg + tid; i < end; i += 256)
        atomicAdd(&lcnt[dst[i] >> BSH], 1u);
    __syncthreads();
    // blocked exclusive scan of nbuck counts: SEG contiguous per thread
    int SEG = (nbuck + 255) >> 8;
    u32 s = 0;
    for (int j = 0; j < SEG; ++j) {
        int b = tid * SEG + j;
        if (b < nbuck) s += lcnt[b];
    }
    part[tid] = s;
    __syncthreads();
    for (int off = 1; off < 256; off <<= 1) {
        u32 t = (tid >= off) ? part[tid - off] : 0;
        __syncthreads();
        part[tid] += t;
        __syncthreads();
    }
    u32 run = part[tid] - s;                  // exclusive over this thread's segment
    for (int j = 0; j < SEG; ++j) {
        int b = tid * SEG + j;
        if (b < nbuck) { u32 cv = lcnt[b]; lpos[b] = run; run += cv; }
    }
    __syncthreads();
    // cursors + global bases
    for (int b = tid; b < nbuck; b += 256) {
        lcnt[b] = lpos[b];
        gbase[b] = base[b] + offs[(size_t)b * nchunk + c];
    }
    __syncthreads();
    // pass 2: scatter into LDS in bucket order
    for (int i = beg + tid; i < end; i += 256) {
        int d = dst[i];
        int b = d >> BSH;
        u32 p = atomicAdd(&lcnt[b], 1u);
        buf[p] = make_int2(src[i] | ((d & (BSZ - 1)) << 17), __float_as_int(ew[i]));
        bb[p] = (unsigned short)b;
    }
    __syncthreads();
    // write-out: slot j of bucket b -> bse[gbase[b] + j - lpos[b]] (coalesced runs)
    int tot = end - beg;
    for (int j = tid; j < tot; j += 256) {
        int b = bb[j];
        bse[gbase[b] + j - lpos[b]] = buf[j];
    }
}

// ---- weighted degree per bucket -> dinv (LDS atomics) ----------------------
__global__ __launch_bounds__(256) void wdeg_kernel(const int2* __restrict__ bse,
                                                   const u32* __restrict__ base,
                                                   float* __restrict__ dinv, int N) {
    __shared__ float wd[BSZ];
    int b = blockIdx.x;
    if (threadIdx.x < BSZ) wd[threadIdx.x] = 0.f;
    __syncthreads();
    int beg = base[b], end = base[b + 1];
    for (int i = beg + threadIdx.x; i < end; i += 256) {
        int2 e = bse[i];
        atomicAdd(&wd[(e.x >> 17) & (BSZ - 1)], __int_as_float(e.y));
    }
    __syncthreads();
    if (threadIdx.x < BSZ) {
        int node = b * BSZ + threadIdx.x;
        if (node < N) dinv[node] = rsqrtf(wd[threadIdx.x] + 1.0f);
    }
}

// ---- layer 1 GEMM via MFMA: hb = bf16(dinv[row] * (x @ W1)) ----------------
__global__ __launch_bounds__(256) void gemm1_kernel(const float* __restrict__ x,
                                                    const float* __restrict__ W1,
                                                    const float* __restrict__ dinv,
                                                    u32* __restrict__ hb, int N) {
    int wave = threadIdx.x >> 6, lane = threadIdx.x & 63;
    int col = lane & 15, kg = lane >> 4;
    int rowbase = blockIdx.x * 64 + wave * 16;

    short8 bW[4][4];
#pragma unroll
    for (int ks = 0; ks < 4; ++ks)
#pragma unroll
        for (int nt = 0; nt < 4; ++nt) {
            const float* wp = W1 + (size_t)(ks * 32 + kg * 8) * HID + nt * 16 + col;
            short8 f;
#pragma unroll
            for (int j = 0; j < 8; ++j) f[j] = bf16b(wp[j * HID]);
            bW[ks][nt] = f;
        }

    f32x4 acc[4];
#pragma unroll
    for (int nt = 0; nt < 4; ++nt) acc[nt] = (f32x4){0.f, 0.f, 0.f, 0.f};

    int arow = rowbase + col;
    if (arow >= N) arow = N - 1;
    const float4* xr = reinterpret_cast<const float4*>(x + (size_t)arow * IN_DIM);
#pragma unroll
    for (int ks = 0; ks < 4; ++ks) {
        float4 xa = xr[ks * 8 + kg * 2];
        float4 xb = xr[ks * 8 + kg * 2 + 1];
        short8 a;
        a[0] = bf16b(xa.x); a[1] = bf16b(xa.y); a[2] = bf16b(xa.z); a[3] = bf16b(xa.w);
        a[4] = bf16b(xb.x); a[5] = bf16b(xb.y); a[6] = bf16b(xb.z); a[7] = bf16b(xb.w);
#pragma unroll
        for (int nt = 0; nt < 4; ++nt)
            acc[nt] = __builtin_amdgcn_mfma_f32_16x16x32_bf16(a, bW[ks][nt], acc[nt], 0, 0, 0);
    }

#pragma unroll
    for (int r = 0; r < 4; ++r) {
        int row = rowbase + kg * 4 + r;
        if (row < N) {
            float di = dinv[row];
            hb[(size_t)row * 32 + col]      = pack_bf16(acc[0][r] * di, acc[2][r] * di);
            hb[(size_t)row * 32 + col + 16] = pack_bf16(acc[1][r] * di, acc[3][r] * di);
        }
    }
}

// ---- aggregation: one block per 64-node bucket, LDS f32 accumulation -------
// aggb[d] = bf16(dinv[d] * (sum_e ew*hb[src_e] + hb[d]))   (hb = dinv*h)
__global__ __launch_bounds__(256) void aggb_kernel(const int2* __restrict__ bse,
                                                   const u32* __restrict__ base,
                                                   const float* __restrict__ dinv,
                                                   const u32* __restrict__ hb,
                                                   u32* __restrict__ aggb, int N) {
    __shared__ float acc[BSZ][HID];           // 16 KB
    int b = blockIdx.x;
    int tid = threadIdx.x;
    float4* az = (float4*)&acc[0][0];
    for (int i = tid; i < BSZ * HID / 4; i += 256) az[i] = make_float4(0.f, 0.f, 0.f, 0.f);
    __syncthreads();

    int beg = base[b], end = base[b + 1];
    int hgid = tid >> 5;                      // half-wave id 0..7
    int l = tid & 31;
    int p = beg + hgid;
    for (; p + 24 < end; p += 32) {           // 4 records per half, stride 8
        int2 e0 = bse[p], e1 = bse[p + 8], e2 = bse[p + 16], e3 = bse[p + 24];
        u32 w0 = hb[(size_t)(e0.x & 0x1FFFF) * 32 + l];
        u32 w1 = hb[(size_t)(e1.x & 0x1FFFF) * 32 + l];
        u32 w2 = hb[(size_t)(e2.x & 0x1FFFF) * 32 + l];
        u32 w3 = hb[(size_t)(e3.x & 0x1FFFF) * 32 + l];
        float c0 = __int_as_float(e0.y), c1 = __int_as_float(e1.y);
        float c2 = __int_as_float(e2.y), c3 = __int_as_float(e3.y);
        int d0 = (e0.x >> 17) & 63, d1 = (e1.x >> 17) & 63;
        int d2 = (e2.x >> 17) & 63, d3 = (e3.x >> 17) & 63;
        atomicAdd(&acc[d0][l], c0 * bf16_lo(w0)); atomicAdd(&acc[d0][l + 32], c0 * bf16_hi(w0));
        atomicAdd(&acc[d1][l], c1 * bf16_lo(w1)); atomicAdd(&acc[d1][l + 32], c1 * bf16_hi(w1));
        atomicAdd(&acc[d2][l], c2 * bf16_lo(w2)); atomicAdd(&acc[d2][l + 32], c2 * bf16_hi(w2));
        atomicAdd(&acc[d3][l], c3 * bf16_lo(w3)); atomicAdd(&acc[d3][l + 32], c3 * bf16_hi(w3));
    }
    for (; p < end; p += 8) {
        int2 e = bse[p];
        u32 w = hb[(size_t)(e.x & 0x1FFFF) * 32 + l];
        float cc = __int_as_float(e.y);
        int dl = (e.x >> 17) & 63;
        atomicAdd(&acc[dl][l], cc * bf16_lo(w));
        atomicAdd(&acc[dl][l + 32], cc * bf16_hi(w));
    }
    __syncthreads();
    // epilogue: add self-loop, scale by dinv[d], pack to bf16
#pragma unroll
    for (int r = 0; r < 8; ++r) {
        int nl = (tid >> 5) + r * 8;
        int node = b * BSZ + nl;
        if (node < N) {
            u32 w = hb[(size_t)node * 32 + l];
            float di = dinv[node];
            float ax = acc[nl][l] + bf16_lo(w);
            float ay = acc[nl][l + 32] + bf16_hi(w);
            aggb[(size_t)node * 32 + l] = pack_bf16(di * ax, di * ay);
        }
    }
}

// ---- layer 2 GEMM via MFMA: hb = bf16(dinv[row]*(relu(aggb + b1) @ W2)) ----
__global__ __launch_bounds__(256) void gemm2_kernel(const u32* __restrict__ aggb,
                                                    const float* __restrict__ b1,
                                                    const float* __restrict__ W2,
                                                    const float* __restrict__ dinv,
                                                    u32* __restrict__ hb, int N) {
    int wave = threadIdx.x >> 6, lane = threadIdx.x & 63;
    int col = lane & 15, kg = lane >> 4;
    int rowbase = blockIdx.x * 64 + wave * 16;

    short8 bW[2][4];
#pragma unroll
    for (int ks = 0; ks < 2; ++ks)
#pragma unroll
        for (int nt = 0; nt < 4; ++nt) {
            const float* wp = W2 + (size_t)(ks * 32 + kg * 8) * HID + nt * 16 + col;
            short8 f;
#pragma unroll
            for (int j = 0; j < 8; ++j) f[j] = bf16b(wp[j * HID]);
            bW[ks][nt] = f;
        }

    f32x4 acc[4];
#pragma unroll
    for (int nt = 0; nt < 4; ++nt) acc[nt] = (f32x4){0.f, 0.f, 0.f, 0.f};

    int arow = rowbase + col;
    if (arow >= N) arow = N - 1;
    const u32* ar = aggb + (size_t)arow * 32 + kg * 8;
    u32 w[8];
#pragma unroll
    for (int j = 0; j < 8; ++j) w[j] = ar[j];      // feats (kg*8+j, kg*8+j+32)
#pragma unroll
    for (int ks = 0; ks < 2; ++ks) {
        short8 a;
#pragma unroll
        for (int j = 0; j < 8; ++j) {
            float f = ks ? bf16_hi(w[j]) : bf16_lo(w[j]);
            a[j] = bf16b(fmaxf(f + b1[ks * 32 + kg * 8 + j], 0.f));
        }
#pragma unroll
        for (int nt = 0; nt < 4; ++nt)
            acc[nt] = __builtin_amdgcn_mfma_f32_16x16x32_bf16(a, bW[ks][nt], acc[nt], 0, 0, 0);
    }

#pragma unroll
    for (int r = 0; r < 4; ++r) {
        int row = rowbase + kg * 4 + r;
        if (row < N) {
            float di = dinv[row];
            hb[(size_t)row * 32 + col]      = pack_bf16(acc[0][r] * di, acc[2][r] * di);
            hb[(size_t)row * 32 + col + 16] = pack_bf16(acc[1][r] * di, acc[3][r] * di);
        }
    }
}

// ---- pooling over sorted batch (packed bf16 input) -------------------------
__global__ void pool_kernel(const u32* __restrict__ aggb, const int* __restrict__ batch,
                            float* __restrict__ pooled, float* __restrict__ cnt,
                            int N, int chunk) {
    int wid = (blockIdx.x * blockDim.x + threadIdx.x) >> 6;
    int lane = threadIdx.x & 63;
    int w = lane & 31, hi = lane >> 5;
    int feat = w + hi * 32;
    int start = wid * chunk;
    if (start >= N) return;
    int end = min(start + chunk, N);
    float acc = 0.f, fc = 0.f;
    int cur = batch[start];
    for (int n = start; n < end; ++n) {
        int g = batch[n];
        if (g != cur) {
            atomicAdd(&pooled[cur * HID + feat], acc);
            if (lane == 0) atomicAdd(&cnt[cur], fc);
            cur = g; acc = 0.f; fc = 0.f;
        }
        u32 hv = aggb[(size_t)n * 32 + w];
        acc += hi ? bf16_hi(hv) : bf16_lo(hv);
        fc += 1.f;
    }
    atomicAdd(&pooled[cur * HID + feat], acc);
    if (lane == 0) atomicAdd(&cnt[cur], fc);
}

// ---- final: out = (pooled/cnt + b2) @ Wfc + bfc ----------------------------
__global__ void final_kernel(const float* __restrict__ pooled, const float* __restrict__ cnt,
                             const float* __restrict__ b2, const float* __restrict__ Wfc,
                             const float* __restrict__ bfc, float* __restrict__ out) {
    int idx = blockIdx.x * blockDim.x + threadIdx.x;
    if (idx >= NGRAPH * OUT_DIM) return;
    int g = idx >> 7, o = idx & 127;
    float inv = 1.0f / fmaxf(cnt[g], 1.0f);
    float acc = 0.f;
#pragma unroll
    for (int k = 0; k < HID; ++k)
        acc += (pooled[g * HID + k] * inv + b2[k]) * Wfc[k * OUT_DIM + o];
    out[idx] = acc + bfc[o];
}

extern "C" void kernel_launch(void* const* d_in, const int* in_sizes, int n_in,
                              void* d_out, int out_size, void* d_ws, size_t ws_size,
                              hipStream_t stream) {
    const float* x    = (const float*)d_in[0];
    const int*   ei   = (const int*)d_in[1];
    const float* ew   = (const float*)d_in[2];
    const int*   bat  = (const int*)d_in[3];
    const float* W1   = (const float*)d_in[4];
    const float* b1   = (const float*)d_in[5];
    const float* W2   = (const float*)d_in[6];
    const float* b2   = (const float*)d_in[7];
    const float* Wfc  = (const float*)d_in[8];
    const float* bfc  = (const float*)d_in[9];
    float* out = (float*)d_out;

    const int N = in_sizes[0] / IN_DIM;
    const int E = in_sizes[2];
    const int* src = ei;
    const int* dst = ei + E;

    const int nbuck  = (N + BSZ - 1) >> BSH;        // 1563 for N=100000 (<=MAXB)
    const int nchunk = (E + CHUNK - 1) / CHUNK;     // 782 for E=3.2M (<=1024)

    char* ws = (char*)d_ws;
    size_t off = 0;
    auto alloc = [&](size_t bytes) {
        char* p = ws + off;
        off += (bytes + 255) / 256 * 256;
        return p;
    };
    u32*   hist    = (u32*)  alloc((size_t)nbuck * nchunk * 4);
    u32*   tot     = (u32*)  alloc(2048 * 4);
    u32*   base    = (u32*)  alloc(2048 * 4);
    float* dinv    = (float*)alloc((size_t)N * 4);
    float* pooled  = (float*)alloc((NGRAPH * HID + NGRAPH) * 4);
    float* cnt     = pooled + NGRAPH * HID;
    int2*  bse     = (int2*) alloc((size_t)E * 8);      // bucket-grouped records
    u32*   hb      = (u32*)  alloc((size_t)N * 32 * 4); // bf16-packed dinv*h
    u32*   aggb    = (u32*)  alloc((size_t)N * 32 * 4); // bf16-packed agg

    hipMemsetAsync(pooled, 0, (NGRAPH * HID + NGRAPH) * 4, stream);

    // ---- bucket-grouped edge build: zero global atomics ----
    bhist_kernel<<<nchunk, 256, 0, stream>>>(dst, hist, E, nchunk, nbuck);
    scanS1<<<nbuck, 512, 0, stream>>>(hist, tot, nchunk, nbuck);
    scanS2<<<1, 1024, 0, stream>>>(tot, base, nbuck);
    bin_kernel<<<nchunk, 256, 0, stream>>>(src, dst, ew, hist, base, bse, E, nchunk, nbuck);
    wdeg_kernel<<<nbuck, 256, 0, stream>>>(bse, base, dinv, N);

    int gemmBlocks = (N + 63) / 64;

    // layer 1
    gemm1_kernel<<<gemmBlocks, 256, 0, stream>>>(x, W1, dinv, hb, N);
    aggb_kernel<<<nbuck, 256, 0, stream>>>(bse, base, dinv, hb, aggb, N);

    // layer 2
    gemm2_kernel<<<gemmBlocks, 256, 0, stream>>>(aggb, b1, W2, dinv, hb, N);
    aggb_kernel<<<nbuck, 256, 0, stream>>>(bse, base, dinv, hb, aggb, N);

    // pooling
    const int POOL_WAVES = 1024;
    int chunk = (N + POOL_WAVES - 1) / POOL_WAVES;
    pool_kernel<<<POOL_WAVES / 4, 256, 0, stream>>>(aggb, bat, pooled, cnt, N, chunk);

    final_kernel<<<(NGRAPH * OUT_DIM + 255) / 256, 256, 0, stream>>>(pooled, cnt, b2, Wfc, bfc, out);
}

// Round 9
// 334.898 us; speedup vs baseline: 7.6019x; 7.6019x over previous
//
#include <hip/hip_runtime.h>

#define IN_DIM 128
#define HID 64
#define OUT_DIM 128
#define NGRAPH 8

#define CHUNK 4096      // edges per chunk for binning passes
#define BSH 6           // 64 nodes per bucket
#define BSZ 64
#define MAXB 1600       // max buckets (N<=102400)

typedef unsigned long long u64;
typedef unsigned int u32;
typedef __attribute__((ext_vector_type(8))) short short8;   // 8 bf16
typedef __attribute__((ext_vector_type(4))) float f32x4;

__device__ inline short bf16b(float f) {                    // f32 -> bf16 bits
    u32 u = __float_as_uint(f);
    return (short)((u + 0x7FFFu + ((u >> 16) & 1u)) >> 16);
}
__device__ inline u32 pack_bf16(float a, float b) {         // low = a, high = b
    u32 ua = (__float_as_uint(a) + 0x8000u) >> 16;
    u32 ub = (__float_as_uint(b) + 0x8000u) & 0xFFFF0000u;
    return ua | ub;
}
__device__ inline float bf16_lo(u32 v) { return __uint_as_float(v << 16); }
__device__ inline float bf16_hi(u32 v) { return __uint_as_float(v & 0xFFFF0000u); }

// ---- Pass A: per-chunk coarse histogram of dst>>6 (LDS int atomics) --------
__global__ __launch_bounds__(256) void bhist_kernel(const int* __restrict__ dst,
                                                    u32* __restrict__ hist,
                                                    int E, int nchunk, int nbuck) {
    __shared__ u32 h[MAXB];
    for (int i = threadIdx.x; i < nbuck; i += 256) h[i] = 0;
    __syncthreads();
    int c = blockIdx.x;
    int beg = c * CHUNK, end = min(beg + CHUNK, E);
    for (int i = beg + threadIdx.x; i < end; i += 256)
        atomicAdd(&h[dst[i] >> BSH], 1u);
    __syncthreads();
    for (int b = threadIdx.x; b < nbuck; b += 256)
        hist[(size_t)b * nchunk + c] = h[b];
}

// ---- S1: per bucket, exclusive scan over chunks (<=1024, 2/thread) ---------
__global__ __launch_bounds__(512) void scanS1(u32* __restrict__ hist, u32* __restrict__ tot,
                                              int nchunk, int nbuck) {
    __shared__ u32 sm[1024];
    int b = blockIdx.x;
    int i0 = threadIdx.x, i1 = threadIdx.x + 512;
    u32 v0 = (i0 < nchunk) ? hist[(size_t)b * nchunk + i0] : 0;
    u32 v1 = (i1 < nchunk) ? hist[(size_t)b * nchunk + i1] : 0;
    sm[i0] = v0; sm[i1] = v1;
    __syncthreads();
    for (int off = 1; off < 1024; off <<= 1) {
        u32 t0 = (i0 >= off) ? sm[i0 - off] : 0;
        u32 t1 = (i1 >= off) ? sm[i1 - off] : 0;
        __syncthreads();
        sm[i0] += t0; sm[i1] += t1;
        __syncthreads();
    }
    if (i0 < nchunk) hist[(size_t)b * nchunk + i0] = sm[i0] - v0;
    if (i1 < nchunk) hist[(size_t)b * nchunk + i1] = sm[i1] - v1;
    if (threadIdx.x == 511) tot[b] = sm[1023];
}

// ---- S2: exclusive scan over bucket totals -> base[0..nbuck] (<=2048) ------
__global__ __launch_bounds__(1024) void scanS2(const u32* __restrict__ tot,
                                               u32* __restrict__ base, int nbuck) {
    __shared__ u32 sm[2048];
    int i0 = threadIdx.x, i1 = threadIdx.x + 1024;
    u32 v0 = (i0 < nbuck) ? tot[i0] : 0;
    u32 v1 = (i1 < nbuck) ? tot[i1] : 0;
    sm[i0] = v0; sm[i1] = v1;
    __syncthreads();
    for (int off = 1; off < 2048; off <<= 1) {
        u32 t0 = (i0 >= off) ? sm[i0 - off] : 0;
        u32 t1 = (i1 >= off) ? sm[i1 - off] : 0;
        __syncthreads();
        sm[i0] += t0; sm[i1] += t1;
        __syncthreads();
    }
    if (i0 <= nbuck) base[i0] = sm[i0] - v0;
    if (i1 <= nbuck) base[i1] = sm[i1] - v1;
}

// ---- Pass B: LDS counting-sort per chunk, then COALESCED write-out ---------
// record: { src | (dst&63)<<17 , ew_bits }   (src < 2^17)
__global__ __launch_bounds__(256) void bin_kernel(const int* __restrict__ src,
                                                  const int* __restrict__ dst,
                                                  const float* __restrict__ ew,
                                                  const u32* __restrict__ offs,
                                                  const u32* __restrict__ base,
                                                  int2* __restrict__ bse,
                                                  int E, int nchunk, int nbuck) {
    __shared__ u32 lcnt[MAXB];                // count, then cursor
    __shared__ u32 lpos[MAXB];                // chunk-local exclusive offsets
    __shared__ u32 gbase[MAXB];               // global target base for this chunk
    __shared__ u32 part[256];
    __shared__ int2 buf[CHUNK];               // bucket-sorted records (32 KB)
    __shared__ unsigned short bb[CHUNK];      // bucket id per sorted slot

    int c = blockIdx.x;
    int tid = threadIdx.x;
    int beg = c * CHUNK, end = min(beg + CHUNK, E);
    for (int b = tid; b < nbuck; b += 256) lcnt[b] = 0;
    __syncthreads();
    // pass 1: count buckets
    for (int i = beg + tid; i < end; i += 256)
        atomicAdd(&lcnt[dst[i] >> BSH], 1u);
    __syncthreads();
    // blocked exclusive scan of nbuck counts: SEG contiguous per thread
    int SEG = (nbuck + 255) >> 8;
    u32 s = 0;
    for (int j = 0; j < SEG; ++j) {
        int b = tid * SEG + j;
        if (b < nbuck) s += lcnt[b];
    }
    part[tid] = s;
    __syncthreads();
    for (int off = 1; off < 256; off <<= 1) {
        u32 t = (tid >= off) ? part[tid - off] : 0;
        __syncthreads();
        part[tid] += t;
        __syncthreads();
    }
    u32 run = part[tid] - s;                  // exclusive over this thread's segment
    for (int j = 0; j < SEG; ++j) {
        int b = tid * SEG + j;
        if (b < nbuck) { u32 cv = lcnt[b]; lpos[b] = run; run += cv; }
    }
    __syncthreads();
    // cursors + global bases
    for (int b = tid; b < nbuck; b += 256) {
        lcnt[b] = lpos[b];
        gbase[b] = base[b] + offs[(size_t)b * nchunk + c];
    }
    __syncthreads();
    // pass 2: scatter into LDS in bucket order
    for (int i = beg + tid; i < end; i += 256) {
        int d = dst[i];
        int b = d >> BSH;
        u32 p = atomicAdd(&lcnt[b], 1u);
        buf[p] = make_int2(src[i] | ((d & (BSZ - 1)) << 17), __float_as_int(ew[i]));
        bb[p] = (unsigned short)b;
    }
    __syncthreads();
    // write-out: slot j of bucket b -> bse[gbase[b] + j - lpos[b]] (coalesced runs)
    int tot = end - beg;
    for (int j = tid; j < tot; j += 256) {
        int b = bb[j];
        bse[gbase[b] + j - lpos[b]] = buf[j];
    }
}

// ---- weighted degree per bucket -> dinv (LDS u32 fixed-point, 2^-20) -------
__global__ __launch_bounds__(256) void wdeg_kernel(const int2* __restrict__ bse,
                                                   const u32* __restrict__ base,
                                                   float* __restrict__ dinv, int N) {
    __shared__ u32 wd[BSZ];
    int b = blockIdx.x;
    if (threadIdx.x < BSZ) wd[threadIdx.x] = 0;
    __syncthreads();
    int beg = base[b], end = base[b + 1];
    for (int i = beg + threadIdx.x; i < end; i += 256) {
        int2 e = bse[i];
        atomicAdd(&wd[(e.x >> 17) & (BSZ - 1)],
                  (u32)__float2int_rn(__int_as_float(e.y) * 1048576.0f));
    }
    __syncthreads();
    if (threadIdx.x < BSZ) {
        int node = b * BSZ + threadIdx.x;
        if (node < N)
            dinv[node] = rsqrtf((float)wd[threadIdx.x] * (1.0f / 1048576.0f) + 1.0f);
    }
}

// ---- layer 1 GEMM via MFMA: hb = bf16(dinv[row] * (x @ W1)) ----------------
__global__ __launch_bounds__(256) void gemm1_kernel(const float* __restrict__ x,
                                                    const float* __restrict__ W1,
                                                    const float* __restrict__ dinv,
                                                    u32* __restrict__ hb, int N) {
    int wave = threadIdx.x >> 6, lane = threadIdx.x & 63;
    int col = lane & 15, kg = lane >> 4;
    int rowbase = blockIdx.x * 64 + wave * 16;

    short8 bW[4][4];
#pragma unroll
    for (int ks = 0; ks < 4; ++ks)
#pragma unroll
        for (int nt = 0; nt < 4; ++nt) {
            const float* wp = W1 + (size_t)(ks * 32 + kg * 8) * HID + nt * 16 + col;
            short8 f;
#pragma unroll
            for (int j = 0; j < 8; ++j) f[j] = bf16b(wp[j * HID]);
            bW[ks][nt] = f;
        }

    f32x4 acc[4];
#pragma unroll
    for (int nt = 0; nt < 4; ++nt) acc[nt] = (f32x4){0.f, 0.f, 0.f, 0.f};

    int arow = rowbase + col;
    if (arow >= N) arow = N - 1;
    const float4* xr = reinterpret_cast<const float4*>(x + (size_t)arow * IN_DIM);
#pragma unroll
    for (int ks = 0; ks < 4; ++ks) {
        float4 xa = xr[ks * 8 + kg * 2];
        float4 xb = xr[ks * 8 + kg * 2 + 1];
        short8 a;
        a[0] = bf16b(xa.x); a[1] = bf16b(xa.y); a[2] = bf16b(xa.z); a[3] = bf16b(xa.w);
        a[4] = bf16b(xb.x); a[5] = bf16b(xb.y); a[6] = bf16b(xb.z); a[7] = bf16b(xb.w);
#pragma unroll
        for (int nt = 0; nt < 4; ++nt)
            acc[nt] = __builtin_amdgcn_mfma_f32_16x16x32_bf16(a, bW[ks][nt], acc[nt], 0, 0, 0);
    }

#pragma unroll
    for (int r = 0; r < 4; ++r) {
        int row = rowbase + kg * 4 + r;
        if (row < N) {
            float di = dinv[row];
            hb[(size_t)row * 32 + col]      = pack_bf16(acc[0][r] * di, acc[2][r] * di);
            hb[(size_t)row * 32 + col + 16] = pack_bf16(acc[1][r] * di, acc[3][r] * di);
        }
    }
}

// ---- aggregation: one block per 64-node bucket, LDS i32 fixed-point (2^-16)
// aggb[d] = bf16(dinv[d] * (sum_e ew*hb[src_e] + hb[d]))   (hb = dinv*h)
__global__ __launch_bounds__(256) void aggb_kernel(const int2* __restrict__ bse,
                                                   const u32* __restrict__ base,
                                                   const float* __restrict__ dinv,
                                                   const u32* __restrict__ hb,
                                                   u32* __restrict__ aggb, int N) {
    __shared__ int acc[BSZ][HID];             // 16 KB, fixed point 2^-16
    int b = blockIdx.x;
    int tid = threadIdx.x;
    int4* az = (int4*)&acc[0][0];
    for (int i = tid; i < BSZ * HID / 4; i += 256) az[i] = make_int4(0, 0, 0, 0);
    __syncthreads();

    int beg = base[b], end = base[b + 1];
    int hg = tid >> 5;                        // half-wave id 0..7
    int l = tid & 31;
    int p = beg + hg;
    for (; p + 56 < end; p += 64) {           // 8 records in flight per half-wave
        int2 e[8];
        u32 w[8];
#pragma unroll
        for (int k = 0; k < 8; ++k) e[k] = bse[p + k * 8];
#pragma unroll
        for (int k = 0; k < 8; ++k) w[k] = hb[(size_t)(e[k].x & 0x1FFFF) * 32 + l];
#pragma unroll
        for (int k = 0; k < 8; ++k) {
            float cs = __int_as_float(e[k].y) * 65536.0f;
            int d = (e[k].x >> 17) & (BSZ - 1);
            atomicAdd((u32*)&acc[d][l],      (u32)__float2int_rn(cs * bf16_lo(w[k])));
            atomicAdd((u32*)&acc[d][l + 32], (u32)__float2int_rn(cs * bf16_hi(w[k])));
        }
    }
    for (; p < end; p += 8) {
        int2 e = bse[p];
        u32 w = hb[(size_t)(e.x & 0x1FFFF) * 32 + l];
        float cs = __int_as_float(e.y) * 65536.0f;
        int d = (e.x >> 17) & (BSZ - 1);
        atomicAdd((u32*)&acc[d][l],      (u32)__float2int_rn(cs * bf16_lo(w)));
        atomicAdd((u32*)&acc[d][l + 32], (u32)__float2int_rn(cs * bf16_hi(w)));
    }
    __syncthreads();
    // epilogue: add self-loop, scale by dinv[d], pack to bf16
#pragma unroll
    for (int r = 0; r < 8; ++r) {
        int nl = hg + r * 8;
        int node = b * BSZ + nl;
        if (node < N) {
            u32 w = hb[(size_t)node * 32 + l];
            float di = dinv[node];
            float ax = (float)acc[nl][l]      * (1.0f / 65536.0f) + bf16_lo(w);
            float ay = (float)acc[nl][l + 32] * (1.0f / 65536.0f) + bf16_hi(w);
            aggb[(size_t)node * 32 + l] = pack_bf16(di * ax, di * ay);
        }
    }
}

// ---- layer 2 GEMM via MFMA: hb = bf16(dinv[row]*(relu(aggb + b1) @ W2)) ----
__global__ __launch_bounds__(256) void gemm2_kernel(const u32* __restrict__ aggb,
                                                    const float* __restrict__ b1,
                                                    const float* __restrict__ W2,
                                                    const float* __restrict__ dinv,
                                                    u32* __restrict__ hb, int N) {
    int wave = threadIdx.x >> 6, lane = threadIdx.x & 63;
    int col = lane & 15, kg = lane >> 4;
    int rowbase = blockIdx.x * 64 + wave * 16;

    short8 bW[2][4];
#pragma unroll
    for (int ks = 0; ks < 2; ++ks)
#pragma unroll
        for (int nt = 0; nt < 4; ++nt) {
            const float* wp = W2 + (size_t)(ks * 32 + kg * 8) * HID + nt * 16 + col;
            short8 f;
#pragma unroll
            for (int j = 0; j < 8; ++j) f[j] = bf16b(wp[j * HID]);
            bW[ks][nt] = f;
        }

    f32x4 acc[4];
#pragma unroll
    for (int nt = 0; nt < 4; ++nt) acc[nt] = (f32x4){0.f, 0.f, 0.f, 0.f};

    int arow = rowbase + col;
    if (arow >= N) arow = N - 1;
    const u32* ar = aggb + (size_t)arow * 32 + kg * 8;
    u32 w[8];
#pragma unroll
    for (int j = 0; j < 8; ++j) w[j] = ar[j];      // feats (kg*8+j, kg*8+j+32)
#pragma unroll
    for (int ks = 0; ks < 2; ++ks) {
        short8 a;
#pragma unroll
        for (int j = 0; j < 8; ++j) {
            float f = ks ? bf16_hi(w[j]) : bf16_lo(w[j]);
            a[j] = bf16b(fmaxf(f + b1[ks * 32 + kg * 8 + j], 0.f));
        }
#pragma unroll
        for (int nt = 0; nt < 4; ++nt)
            acc[nt] = __builtin_amdgcn_mfma_f32_16x16x32_bf16(a, bW[ks][nt], acc[nt], 0, 0, 0);
    }

#pragma unroll
    for (int r = 0; r < 4; ++r) {
        int row = rowbase + kg * 4 + r;
        if (row < N) {
            float di = dinv[row];
            hb[(size_t)row * 32 + col]      = pack_bf16(acc[0][r] * di, acc[2][r] * di);
            hb[(size_t)row * 32 + col + 16] = pack_bf16(acc[1][r] * di, acc[3][r] * di);
        }
    }
}

// ---- pooling over sorted batch (packed bf16 input) -------------------------
__global__ void pool_kernel(const u32* __restrict__ aggb, const int* __restrict__ batch,
                            float* __restrict__ pooled, float* __restrict__ cnt,
                            int N, int chunk) {
    int wid = (blockIdx.x * blockDim.x + threadIdx.x) >> 6;
    int lane = threadIdx.x & 63;
    int w = lane & 31, hi = lane >> 5;
    int feat = w + hi * 32;
    int start = wid * chunk;
    if (start >= N) return;
    int end = min(start + chunk, N);
    float acc = 0.f, fc = 0.f;
    int cur = batch[start];
    for (int n = start; n < end; ++n) {
        int g = batch[n];
        if (g != cur) {
            atomicAdd(&pooled[cur * HID + feat], acc);
            if (lane == 0) atomicAdd(&cnt[cur], fc);
            cur = g; acc = 0.f; fc = 0.f;
        }
        u32 hv = aggb[(size_t)n * 32 + w];
        acc += hi ? bf16_hi(hv) : bf16_lo(hv);
        fc += 1.f;
    }
    atomicAdd(&pooled[cur * HID + feat], acc);
    if (lane == 0) atomicAdd(&cnt[cur], fc);
}

// ---- final: out = (pooled/cnt + b2) @ Wfc + bfc ----------------------------
__global__ void final_kernel(const float* __restrict__ pooled, const float* __restrict__ cnt,
                             const float* __restrict__ b2, const float* __restrict__ Wfc,
                             const float* __restrict__ bfc, float* __restrict__ out) {
    int idx = blockIdx.x * blockDim.x + threadIdx.x;
    if (idx >= NGRAPH * OUT_DIM) return;
    int g = idx >> 7, o = idx & 127;
    float inv = 1.0f / fmaxf(cnt[g], 1.0f);
    float acc = 0.f;
#pragma unroll
    for (int k = 0; k < HID; ++k)
        acc += (pooled[g * HID + k] * inv + b2[k]) * Wfc[k * OUT_DIM + o];
    out[idx] = acc + bfc[o];
}

extern "C" void kernel_launch(void* const* d_in, const int* in_sizes, int n_in,
                              void* d_out, int out_size, void* d_ws, size_t ws_size,
                              hipStream_t stream) {
    const float* x    = (const float*)d_in[0];
    const int*   ei   = (const int*)d_in[1];
    const float* ew   = (const float*)d_in[2];
    const int*   bat  = (const int*)d_in[3];
    const float* W1   = (const float*)d_in[4];
    const float* b1   = (const float*)d_in[5];
    const float* W2   = (const float*)d_in[6];
    const float* b2   = (const float*)d_in[7];
    const float* Wfc  = (const float*)d_in[8];
    const float* bfc  = (const float*)d_in[9];
    float* out = (float*)d_out;

    const int N = in_sizes[0] / IN_DIM;
    const int E = in_sizes[2];
    const int* src = ei;
    const int* dst = ei + E;

    const int nbuck  = (N + BSZ - 1) >> BSH;        // 1563 for N=100000 (<=MAXB)
    const int nchunk = (E + CHUNK - 1) / CHUNK;     // 782 for E=3.2M (<=1024)

    char* ws = (char*)d_ws;
    size_t off = 0;
    auto alloc = [&](size_t bytes) {
        char* p = ws + off;
        off += (bytes + 255) / 256 * 256;
        return p;
    };
    u32*   hist    = (u32*)  alloc((size_t)nbuck * nchunk * 4);
    u32*   tot     = (u32*)  alloc(2048 * 4);
    u32*   base    = (u32*)  alloc(2048 * 4);
    float* dinv    = (float*)alloc((size_t)N * 4);
    float* pooled  = (float*)alloc((NGRAPH * HID + NGRAPH) * 4);
    float* cnt     = pooled + NGRAPH * HID;
    int2*  bse     = (int2*) alloc((size_t)E * 8);      // bucket-grouped records
    u32*   hb      = (u32*)  alloc((size_t)N * 32 * 4); // bf16-packed dinv*h
    u32*   aggb    = (u32*)  alloc((size_t)N * 32 * 4); // bf16-packed agg

    hipMemsetAsync(pooled, 0, (NGRAPH * HID + NGRAPH) * 4, stream);

    // ---- bucket-grouped edge build: zero global atomics ----
    bhist_kernel<<<nchunk, 256, 0, stream>>>(dst, hist, E, nchunk, nbuck);
    scanS1<<<nbuck, 512, 0, stream>>>(hist, tot, nchunk, nbuck);
    scanS2<<<1, 1024, 0, stream>>>(tot, base, nbuck);
    bin_kernel<<<nchunk, 256, 0, stream>>>(src, dst, ew, hist, base, bse, E, nchunk, nbuck);
    wdeg_kernel<<<nbuck, 256, 0, stream>>>(bse, base, dinv, N);

    int gemmBlocks = (N + 63) / 64;

    // layer 1
    gemm1_kernel<<<gemmBlocks, 256, 0, stream>>>(x, W1, dinv, hb, N);
    aggb_kernel<<<nbuck, 256, 0, stream>>>(bse, base, dinv, hb, aggb, N);

    // layer 2
    gemm2_kernel<<<gemmBlocks, 256, 0, stream>>>(aggb, b1, W2, dinv, hb, N);
    aggb_kernel<<<nbuck, 256, 0, stream>>>(bse, base, dinv, hb, aggb, N);

    // pooling
    const int POOL_WAVES = 1024;
    int chunk = (N + POOL_WAVES - 1) / POOL_WAVES;
    pool_kernel<<<POOL_WAVES / 4, 256, 0, stream>>>(aggb, bat, pooled, cnt, N, chunk);

    final_kernel<<<(NGRAPH * OUT_DIM + 255) / 256, 256, 0, stream>>>(pooled, cnt, b2, Wfc, bfc, out);
}

// Round 10
// 306.284 us; speedup vs baseline: 8.3120x; 1.0934x over previous
//
#include <hip/hip_runtime.h>

#define IN_DIM 128
#define HID 64
#define OUT_DIM 128
#define NGRAPH 8

#define CHUNK 4096      // edges per chunk for binning passes
#define BSH 7           // 128 nodes per bucket
#define BSZ 128
#define MAXB 800        // max buckets (N<=102400)

typedef unsigned long long u64;
typedef unsigned int u32;
typedef __attribute__((ext_vector_type(8))) short short8;   // 8 bf16
typedef __attribute__((ext_vector_type(4))) float f32x4;

__device__ inline short bf16b(float f) {                    // f32 -> bf16 bits
    u32 u = __float_as_uint(f);
    return (short)((u + 0x7FFFu + ((u >> 16) & 1u)) >> 16);
}
__device__ inline u32 pack_bf16(float a, float b) {         // low = a, high = b
    u32 ua = (__float_as_uint(a) + 0x8000u) >> 16;
    u32 ub = (__float_as_uint(b) + 0x8000u) & 0xFFFF0000u;
    return ua | ub;
}
__device__ inline float bf16_lo(u32 v) { return __uint_as_float(v << 16); }
__device__ inline float bf16_hi(u32 v) { return __uint_as_float(v & 0xFFFF0000u); }

// ---- Pass A: per-chunk coarse histogram of dst>>7 (LDS int atomics) --------
__global__ __launch_bounds__(256) void bhist_kernel(const int* __restrict__ dst,
                                                    u32* __restrict__ hist,
                                                    int E, int nchunk, int nbuck) {
    __shared__ u32 h[MAXB];
    for (int i = threadIdx.x; i < nbuck; i += 256) h[i] = 0;
    __syncthreads();
    int c = blockIdx.x;
    int beg = c * CHUNK, end = min(beg + CHUNK, E);
    for (int i = beg + threadIdx.x; i < end; i += 256)
        atomicAdd(&h[dst[i] >> BSH], 1u);
    __syncthreads();
    for (int b = threadIdx.x; b < nbuck; b += 256)
        hist[(size_t)b * nchunk + c] = h[b];
}

// ---- S1: per bucket, exclusive scan over chunks (<=1024, 2/thread) ---------
__global__ __launch_bounds__(512) void scanS1(u32* __restrict__ hist, u32* __restrict__ tot,
                                              int nchunk, int nbuck) {
    __shared__ u32 sm[1024];
    int b = blockIdx.x;
    int i0 = threadIdx.x, i1 = threadIdx.x + 512;
    u32 v0 = (i0 < nchunk) ? hist[(size_t)b * nchunk + i0] : 0;
    u32 v1 = (i1 < nchunk) ? hist[(size_t)b * nchunk + i1] : 0;
    sm[i0] = v0; sm[i1] = v1;
    __syncthreads();
    for (int off = 1; off < 1024; off <<= 1) {
        u32 t0 = (i0 >= off) ? sm[i0 - off] : 0;
        u32 t1 = (i1 >= off) ? sm[i1 - off] : 0;
        __syncthreads();
        sm[i0] += t0; sm[i1] += t1;
        __syncthreads();
    }
    if (i0 < nchunk) hist[(size_t)b * nchunk + i0] = sm[i0] - v0;
    if (i1 < nchunk) hist[(size_t)b * nchunk + i1] = sm[i1] - v1;
    if (threadIdx.x == 511) tot[b] = sm[1023];
}

// ---- S2: exclusive scan over bucket totals -> base[0..nbuck] (<=2048) ------
__global__ __launch_bounds__(1024) void scanS2(const u32* __restrict__ tot,
                                               u32* __restrict__ base, int nbuck) {
    __shared__ u32 sm[2048];
    int i0 = threadIdx.x, i1 = threadIdx.x + 1024;
    u32 v0 = (i0 < nbuck) ? tot[i0] : 0;
    u32 v1 = (i1 < nbuck) ? tot[i1] : 0;
    sm[i0] = v0; sm[i1] = v1;
    __syncthreads();
    for (int off = 1; off < 2048; off <<= 1) {
        u32 t0 = (i0 >= off) ? sm[i0 - off] : 0;
        u32 t1 = (i1 >= off) ? sm[i1 - off] : 0;
        __syncthreads();
        sm[i0] += t0; sm[i1] += t1;
        __syncthreads();
    }
    if (i0 <= nbuck) base[i0] = sm[i0] - v0;
    if (i1 <= nbuck) base[i1] = sm[i1] - v1;
}

// ---- Pass B: LDS counting-sort per chunk, then COALESCED write-out ---------
// record: { src | (dst&127)<<17 , ew_bits }   (src < 2^17)
__global__ __launch_bounds__(256) void bin_kernel(const int* __restrict__ src,
                                                  const int* __restrict__ dst,
                                                  const float* __restrict__ ew,
                                                  const u32* __restrict__ offs,
                                                  const u32* __restrict__ base,
                                                  int2* __restrict__ bse,
                                                  int E, int nchunk, int nbuck) {
    __shared__ u32 lcnt[MAXB];                // count, then cursor
    __shared__ u32 lpos[MAXB];                // chunk-local exclusive offsets
    __shared__ u32 gbase[MAXB];               // global target base for this chunk
    __shared__ u32 part[256];
    __shared__ int2 buf[CHUNK];               // bucket-sorted records (32 KB)
    __shared__ unsigned short bb[CHUNK];      // bucket id per sorted slot

    int c = blockIdx.x;
    int tid = threadIdx.x;
    int beg = c * CHUNK, end = min(beg + CHUNK, E);
    for (int b = tid; b < nbuck; b += 256) lcnt[b] = 0;
    __syncthreads();
    // pass 1: count buckets
    for (int i = beg + tid; i < end; i += 256)
        atomicAdd(&lcnt[dst[i] >> BSH], 1u);
    __syncthreads();
    // blocked exclusive scan of nbuck counts: SEG contiguous per thread
    int SEG = (nbuck + 255) >> 8;
    u32 s = 0;
    for (int j = 0; j < SEG; ++j) {
        int b = tid * SEG + j;
        if (b < nbuck) s += lcnt[b];
    }
    part[tid] = s;
    __syncthreads();
    for (int off = 1; off < 256; off <<= 1) {
        u32 t = (tid >= off) ? part[tid - off] : 0;
        __syncthreads();
        part[tid] += t;
        __syncthreads();
    }
    u32 run = part[tid] - s;                  // exclusive over this thread's segment
    for (int j = 0; j < SEG; ++j) {
        int b = tid * SEG + j;
        if (b < nbuck) { u32 cv = lcnt[b]; lpos[b] = run; run += cv; }
    }
    __syncthreads();
    // cursors + global bases
    for (int b = tid; b < nbuck; b += 256) {
        lcnt[b] = lpos[b];
        gbase[b] = base[b] + offs[(size_t)b * nchunk + c];
    }
    __syncthreads();
    // pass 2: scatter into LDS in bucket order
    for (int i = beg + tid; i < end; i += 256) {
        int d = dst[i];
        int b = d >> BSH;
        u32 p = atomicAdd(&lcnt[b], 1u);
        buf[p] = make_int2(src[i] | ((d & (BSZ - 1)) << 17), __float_as_int(ew[i]));
        bb[p] = (unsigned short)b;
    }
    __syncthreads();
    // write-out: slot j of bucket b -> bse[gbase[b] + j - lpos[b]] (coalesced runs)
    int tot = end - beg;
    for (int j = tid; j < tot; j += 256) {
        int b = bb[j];
        bse[gbase[b] + j - lpos[b]] = buf[j];
    }
}

// ---- Pass C: per 128-node bucket: hist + wdeg (u32 LDS), scan -> CSR -------
__global__ __launch_bounds__(256) void csr_kernel(const int2* __restrict__ bse,
                                                  const u32* __restrict__ base,
                                                  int* __restrict__ row_ptr,
                                                  float* __restrict__ dinv,
                                                  int2* __restrict__ edges, int N) {
    __shared__ u32 cnt[BSZ];
    __shared__ u32 wd[BSZ];                   // fixed point 2^-20
    __shared__ u32 rp[BSZ];
    int b = blockIdx.x;
    int tid = threadIdx.x;
    int beg = base[b], end = base[b + 1];
    if (tid < BSZ) { cnt[tid] = 0; wd[tid] = 0; }
    __syncthreads();
    for (int i = beg + tid; i < end; i += 256) {
        int2 e = bse[i];
        int dl = (e.x >> 17) & (BSZ - 1);
        atomicAdd(&cnt[dl], 1u);
        atomicAdd(&wd[dl], (u32)__float2int_rn(__int_as_float(e.y) * 1048576.0f));
    }
    __syncthreads();
    u32 v = 0;
    if (tid < BSZ) { v = cnt[tid]; rp[tid] = v; }
    __syncthreads();
    for (int off = 1; off < BSZ; off <<= 1) {
        u32 t = 0;
        if (tid < BSZ && tid >= off) t = rp[tid - off];
        __syncthreads();
        if (tid < BSZ) rp[tid] += t;
        __syncthreads();
    }
    if (tid < BSZ) {
        int node = b * BSZ + tid;
        u32 excl = rp[tid] - v;
        if (node <= N) row_ptr[node] = beg + (int)excl;
        if (node < N)
            dinv[node] = rsqrtf((float)wd[tid] * (1.0f / 1048576.0f) + 1.0f);
    }
    __syncthreads();
    if (tid < BSZ) cnt[tid] = rp[tid] - v;    // cursor = exclusive prefix
    __syncthreads();
    for (int i = beg + tid; i < end; i += 256) {
        int2 e = bse[i];
        int dl = (e.x >> 17) & (BSZ - 1);
        u32 r = atomicAdd(&cnt[dl], 1u);
        edges[beg + r] = make_int2(e.x & 0x1FFFF, e.y);
    }
}

// ---- layer 1 GEMM via MFMA: hb = bf16(dinv[row] * (x @ W1)) ----------------
__global__ __launch_bounds__(256) void gemm1_kernel(const float* __restrict__ x,
                                                    const float* __restrict__ W1,
                                                    const float* __restrict__ dinv,
                                                    u32* __restrict__ hb, int N) {
    int wave = threadIdx.x >> 6, lane = threadIdx.x & 63;
    int col = lane & 15, kg = lane >> 4;
    int rowbase = blockIdx.x * 64 + wave * 16;

    short8 bW[4][4];
#pragma unroll
    for (int ks = 0; ks < 4; ++ks)
#pragma unroll
        for (int nt = 0; nt < 4; ++nt) {
            const float* wp = W1 + (size_t)(ks * 32 + kg * 8) * HID + nt * 16 + col;
            short8 f;
#pragma unroll
            for (int j = 0; j < 8; ++j) f[j] = bf16b(wp[j * HID]);
            bW[ks][nt] = f;
        }

    f32x4 acc[4];
#pragma unroll
    for (int nt = 0; nt < 4; ++nt) acc[nt] = (f32x4){0.f, 0.f, 0.f, 0.f};

    int arow = rowbase + col;
    if (arow >= N) arow = N - 1;
    const float4* xr = reinterpret_cast<const float4*>(x + (size_t)arow * IN_DIM);
#pragma unroll
    for (int ks = 0; ks < 4; ++ks) {
        float4 xa = xr[ks * 8 + kg * 2];
        float4 xb = xr[ks * 8 + kg * 2 + 1];
        short8 a;
        a[0] = bf16b(xa.x); a[1] = bf16b(xa.y); a[2] = bf16b(xa.z); a[3] = bf16b(xa.w);
        a[4] = bf16b(xb.x); a[5] = bf16b(xb.y); a[6] = bf16b(xb.z); a[7] = bf16b(xb.w);
#pragma unroll
        for (int nt = 0; nt < 4; ++nt)
            acc[nt] = __builtin_amdgcn_mfma_f32_16x16x32_bf16(a, bW[ks][nt], acc[nt], 0, 0, 0);
    }

#pragma unroll
    for (int r = 0; r < 4; ++r) {
        int row = rowbase + kg * 4 + r;
        if (row < N) {
            float di = dinv[row];
            hb[(size_t)row * 32 + col]      = pack_bf16(acc[0][r] * di, acc[2][r] * di);
            hb[(size_t)row * 32 + col + 16] = pack_bf16(acc[1][r] * di, acc[3][r] * di);
        }
    }
}

// ---- aggregation: aggb[d] = bf16(dinv[d]*(sum ew*hb[src] + hb[d])) ---------
// wave per node, contiguous half-split, 8 gathers in flight (register acc)
__global__ void agg_kernel(const int* __restrict__ row_ptr, const int2* __restrict__ edges,
                           const float* __restrict__ dinv, const u32* __restrict__ hb,
                           u32* __restrict__ aggb, int N) {
    int gid = blockIdx.x * blockDim.x + threadIdx.x;
    int node = gid >> 6, lane = gid & 63;
    if (node >= N) return;
    int half = lane >> 5, l = lane & 31;
    int beg = row_ptr[node], end = row_ptr[node + 1];
    int mid = beg + ((end - beg + 1) >> 1);
    int lo = half ? mid : beg;
    int hi = half ? end : mid;
    float ax = 0.f, ay = 0.f;
    if (half == 0) {                        // self-loop: hb already dinv-scaled
        u32 hv = hb[(size_t)node * 32 + l];
        ax = bf16_lo(hv);
        ay = bf16_hi(hv);
    }
    int i = lo;
    for (; i + 8 <= hi; i += 8) {
        int2 e0 = edges[i+0], e1 = edges[i+1], e2 = edges[i+2], e3 = edges[i+3];
        int2 e4 = edges[i+4], e5 = edges[i+5], e6 = edges[i+6], e7 = edges[i+7];
        u32 h0 = hb[(size_t)e0.x * 32 + l], h1 = hb[(size_t)e1.x * 32 + l];
        u32 h2 = hb[(size_t)e2.x * 32 + l], h3 = hb[(size_t)e3.x * 32 + l];
        u32 h4 = hb[(size_t)e4.x * 32 + l], h5 = hb[(size_t)e5.x * 32 + l];
        u32 h6 = hb[(size_t)e6.x * 32 + l], h7 = hb[(size_t)e7.x * 32 + l];
        float c0 = __int_as_float(e0.y), c1 = __int_as_float(e1.y);
        float c2 = __int_as_float(e2.y), c3 = __int_as_float(e3.y);
        float c4 = __int_as_float(e4.y), c5 = __int_as_float(e5.y);
        float c6 = __int_as_float(e6.y), c7 = __int_as_float(e7.y);
        ax += c0 * bf16_lo(h0); ay += c0 * bf16_hi(h0);
        ax += c1 * bf16_lo(h1); ay += c1 * bf16_hi(h1);
        ax += c2 * bf16_lo(h2); ay += c2 * bf16_hi(h2);
        ax += c3 * bf16_lo(h3); ay += c3 * bf16_hi(h3);
        ax += c4 * bf16_lo(h4); ay += c4 * bf16_hi(h4);
        ax += c5 * bf16_lo(h5); ay += c5 * bf16_hi(h5);
        ax += c6 * bf16_lo(h6); ay += c6 * bf16_hi(h6);
        ax += c7 * bf16_lo(h7); ay += c7 * bf16_hi(h7);
    }
    if (i < hi) {                           // predicated tail: full MLP, no serial chain
        int2 e[8];
#pragma unroll
        for (int k = 0; k < 8; ++k) {
            int j = i + k;
            e[k] = edges[j < hi ? j : i];
            if (j >= hi) e[k].y = 0;        // 0.0f coefficient
        }
        u32 hh[8];
#pragma unroll
        for (int k = 0; k < 8; ++k) hh[k] = hb[(size_t)e[k].x * 32 + l];
#pragma unroll
        for (int k = 0; k < 8; ++k) {
            float c = __int_as_float(e[k].y);
            ax += c * bf16_lo(hh[k]);
            ay += c * bf16_hi(hh[k]);
        }
    }
    ax += __shfl_xor(ax, 32);
    ay += __shfl_xor(ay, 32);
    float di = dinv[node];
    if (lane < 32) aggb[(size_t)node * 32 + l] = pack_bf16(di * ax, di * ay);
}

// ---- layer 2 GEMM via MFMA: hb = bf16(dinv[row]*(relu(aggb + b1) @ W2)) ----
__global__ __launch_bounds__(256) void gemm2_kernel(const u32* __restrict__ aggb,
                                                    const float* __restrict__ b1,
                                                    const float* __restrict__ W2,
                                                    const float* __restrict__ dinv,
                                                    u32* __restrict__ hb, int N) {
    int wave = threadIdx.x >> 6, lane = threadIdx.x & 63;
    int col = lane & 15, kg = lane >> 4;
    int rowbase = blockIdx.x * 64 + wave * 16;

    short8 bW[2][4];
#pragma unroll
    for (int ks = 0; ks < 2; ++ks)
#pragma unroll
        for (int nt = 0; nt < 4; ++nt) {
            const float* wp = W2 + (size_t)(ks * 32 + kg * 8) * HID + nt * 16 + col;
            short8 f;
#pragma unroll
            for (int j = 0; j < 8; ++j) f[j] = bf16b(wp[j * HID]);
            bW[ks][nt] = f;
        }

    f32x4 acc[4];
#pragma unroll
    for (int nt = 0; nt < 4; ++nt) acc[nt] = (f32x4){0.f, 0.f, 0.f, 0.f};

    int arow = rowbase + col;
    if (arow >= N) arow = N - 1;
    const u32* ar = aggb + (size_t)arow * 32 + kg * 8;
    u32 w[8];
#pragma unroll
    for (int j = 0; j < 8; ++j) w[j] = ar[j];      // feats (kg*8+j, kg*8+j+32)
#pragma unroll
    for (int ks = 0; ks < 2; ++ks) {
        short8 a;
#pragma unroll
        for (int j = 0; j < 8; ++j) {
            float f = ks ? bf16_hi(w[j]) : bf16_lo(w[j]);
            a[j] = bf16b(fmaxf(f + b1[ks * 32 + kg * 8 + j], 0.f));
        }
#pragma unroll
        for (int nt = 0; nt < 4; ++nt)
            acc[nt] = __builtin_amdgcn_mfma_f32_16x16x32_bf16(a, bW[ks][nt], acc[nt], 0, 0, 0);
    }

#pragma unroll
    for (int r = 0; r < 4; ++r) {
        int row = rowbase + kg * 4 + r;
        if (row < N) {
            float di = dinv[row];
            hb[(size_t)row * 32 + col]      = pack_bf16(acc[0][r] * di, acc[2][r] * di);
            hb[(size_t)row * 32 + col + 16] = pack_bf16(acc[1][r] * di, acc[3][r] * di);
        }
    }
}

// ---- pooling over sorted batch (packed bf16 input) -------------------------
__global__ void pool_kernel(const u32* __restrict__ aggb, const int* __restrict__ batch,
                            float* __restrict__ pooled, float* __restrict__ cnt,
                            int N, int chunk) {
    int wid = (blockIdx.x * blockDim.x + threadIdx.x) >> 6;
    int lane = threadIdx.x & 63;
    int w = lane & 31, hi = lane >> 5;
    int feat = w + hi * 32;
    int start = wid * chunk;
    if (start >= N) return;
    int end = min(start + chunk, N);
    float acc = 0.f, fc = 0.f;
    int cur = batch[start];
    for (int n = start; n < end; ++n) {
        int g = batch[n];
        if (g != cur) {
            atomicAdd(&pooled[cur * HID + feat], acc);
            if (lane == 0) atomicAdd(&cnt[cur], fc);
            cur = g; acc = 0.f; fc = 0.f;
        }
        u32 hv = aggb[(size_t)n * 32 + w];
        acc += hi ? bf16_hi(hv) : bf16_lo(hv);
        fc += 1.f;
    }
    atomicAdd(&pooled[cur * HID + feat], acc);
    if (lane == 0) atomicAdd(&cnt[cur], fc);
}

// ---- final: out = (pooled/cnt + b2) @ Wfc + bfc ----------------------------
__global__ void final_kernel(const float* __restrict__ pooled, const float* __restrict__ cnt,
                             const float* __restrict__ b2, const float* __restrict__ Wfc,
                             const float* __restrict__ bfc, float* __restrict__ out) {
    int idx = blockIdx.x * blockDim.x + threadIdx.x;
    if (idx >= NGRAPH * OUT_DIM) return;
    int g = idx >> 7, o = idx & 127;
    float inv = 1.0f / fmaxf(cnt[g], 1.0f);
    float acc = 0.f;
#pragma unroll
    for (int k = 0; k < HID; ++k)
        acc += (pooled[g * HID + k] * inv + b2[k]) * Wfc[k * OUT_DIM + o];
    out[idx] = acc + bfc[o];
}

extern "C" void kernel_launch(void* const* d_in, const int* in_sizes, int n_in,
                              void* d_out, int out_size, void* d_ws, size_t ws_size,
                              hipStream_t stream) {
    const float* x    = (const float*)d_in[0];
    const int*   ei   = (const int*)d_in[1];
    const float* ew   = (const float*)d_in[2];
    const int*   bat  = (const int*)d_in[3];
    const float* W1   = (const float*)d_in[4];
    const float* b1   = (const float*)d_in[5];
    const float* W2   = (const float*)d_in[6];
    const float* b2   = (const float*)d_in[7];
    const float* Wfc  = (const float*)d_in[8];
    const float* bfc  = (const float*)d_in[9];
    float* out = (float*)d_out;

    const int N = in_sizes[0] / IN_DIM;
    const int E = in_sizes[2];
    const int* src = ei;
    const int* dst = ei + E;

    const int nbuck  = (N + BSZ - 1) >> BSH;        // 782 for N=100000 (<=MAXB)
    const int nchunk = (E + CHUNK - 1) / CHUNK;     // 782 for E=3.2M (<=1024)

    char* ws = (char*)d_ws;
    size_t off = 0;
    auto alloc = [&](size_t bytes) {
        char* p = ws + off;
        off += (bytes + 255) / 256 * 256;
        return p;
    };
    u32*   hist    = (u32*)  alloc((size_t)nbuck * nchunk * 4);
    u32*   tot     = (u32*)  alloc(2048 * 4);
    u32*   base    = (u32*)  alloc(2048 * 4);
    int*   row_ptr = (int*)  alloc((size_t)(N + 1) * 4);
    float* dinv    = (float*)alloc((size_t)N * 4);
    float* pooled  = (float*)alloc((NGRAPH * HID + NGRAPH) * 4);
    float* cnt     = pooled + NGRAPH * HID;
    int2*  bse     = (int2*) alloc((size_t)E * 8);      // bucket-grouped records
    int2*  edges   = (int2*) alloc((size_t)E * 8);      // final CSR {src, ew}
    u32*   hb      = (u32*)  alloc((size_t)N * 32 * 4); // bf16-packed dinv*h
    u32*   aggb    = (u32*)  alloc((size_t)N * 32 * 4); // bf16-packed agg

    hipMemsetAsync(pooled, 0, (NGRAPH * HID + NGRAPH) * 4, stream);

    // ---- CSR build: zero global atomics, all LDS atomics native u32 ----
    bhist_kernel<<<nchunk, 256, 0, stream>>>(dst, hist, E, nchunk, nbuck);
    scanS1<<<nbuck, 512, 0, stream>>>(hist, tot, nchunk, nbuck);
    scanS2<<<1, 1024, 0, stream>>>(tot, base, nbuck);
    bin_kernel<<<nchunk, 256, 0, stream>>>(src, dst, ew, hist, base, bse, E, nchunk, nbuck);
    csr_kernel<<<nbuck, 256, 0, stream>>>(bse, base, row_ptr, dinv, edges, N);

    int gemmBlocks = (N + 63) / 64;
    int rowBlocks = (int)(((size_t)N * 64 + 255) / 256);

    // layer 1
    gemm1_kernel<<<gemmBlocks, 256, 0, stream>>>(x, W1, dinv, hb, N);
    agg_kernel<<<rowBlocks, 256, 0, stream>>>(row_ptr, edges, dinv, hb, aggb, N);

    // layer 2
    gemm2_kernel<<<gemmBlocks, 256, 0, stream>>>(aggb, b1, W2, dinv, hb, N);
    agg_kernel<<<rowBlocks, 256, 0, stream>>>(row_ptr, edges, dinv, hb, aggb, N);

    // pooling
    const int POOL_WAVES = 1024;
    int chunk = (N + POOL_WAVES - 1) / POOL_WAVES;
    pool_kernel<<<POOL_WAVES / 4, 256, 0, stream>>>(aggb, bat, pooled, cnt, N, chunk);

    final_kernel<<<(NGRAPH * OUT_DIM + 255) / 256, 256, 0, stream>>>(pooled, cnt, b2, Wfc, bfc, out);
}